// Round 9
// baseline (388.370 us; speedup 1.0000x reference)
//
#include <hip/hip_runtime.h>
#include <stdint.h>

// Problem constants (from reference)
#define TT 8192          // time length
#define CC 72            // channels
#define PP 7             // patch size
#define NN (TT - PP + 1) // 8186 patches
#define DD (CC * PP)     // 504 patch dim

#define TI 122           // output tile (both dims)
#define SG 128           // S grid = TI + PP - 1 = 128 exactly
#define SPAD 132         // padded S row stride (floats), 16B-aligned rows
#define NTILE ((NN + TI - 1) / TI)   // 68
#define NT2   (NTILE * NTILE)        // 4624

#define STAGE_BYTES (CC * SG * 4)            // 36864 per buffer
#define SMEM_UNION  (2 * STAGE_BYTES)        // 73728 (Xs+Ys, aliased by S)

// tail scratch block: 192 KiB total, placed at end of ws so dist can use the front
#define TAIL_BYTES 196608

#define SROWS 4          // dist rows per stream block (colmin reuse + MLP)
#define NPF 18           // stage loads per thread per matrix (CC*SG/2/256)

constexpr float INV_D = 1.0f / (float)DD;
constexpr float ALPHA_C = 0.01f;
constexpr float QSCALE = 67108864.0f;        // 2^26 fixed-point for deterministic mean

// ------------------------------------------------------------------
// prep: patch norms sx/sy (split across gridDim.y; per-i accumulation
// order unchanged -> bit-identical); init colmin, packed, qsum, ticket.
// ------------------------------------------------------------------
__global__ void prep_kernel(const float* __restrict__ X, const float* __restrict__ Y,
                            float* __restrict__ sx, float* __restrict__ sy,
                            unsigned* __restrict__ colmin,
                            unsigned long long* __restrict__ packed,
                            unsigned long long* __restrict__ qsum,
                            unsigned* __restrict__ ticket) {
    int i = blockIdx.x * 256 + threadIdx.x;
    if (blockIdx.y == 0) {
        if (i == 0) { *qsum = 0ULL; *ticket = 0u; }
        if (i < TT) { colmin[i] = 0x7f800000u; packed[i] = ~0ULL; }
        if (i < NN) {
            float ax = 0.0f;
            for (int c = 0; c < CC; ++c) {
                const float* xr = X + c * TT + i;
#pragma unroll
                for (int k = 0; k < PP; ++k) { float v = xr[k]; ax += v * v; }
            }
            sx[i] = ax;
        }
    } else {
        if (i < NN) {
            float ay = 0.0f;
            for (int c = 0; c < CC; ++c) {
                const float* yr = Y + c * TT + i;
#pragma unroll
                for (int k = 0; k < PP; ++k) { float w = yr[k]; ay += w * w; }
            }
            sy[i] = ay;
        }
    }
}

// ------------------------------------------------------------------
// stage-value loader: EXACT same addresses/clamps as the validated
// staging loop; only the timing of the loads moves (prefetch).
// ------------------------------------------------------------------
__device__ __forceinline__ void stage_prefetch(const float* __restrict__ X,
                                               const float* __restrict__ Y,
                                               int i0, int j0, int tid,
                                               float2 px[NPF], float2 py[NPF]) {
#pragma unroll
    for (int k = 0; k < NPF; ++k) {
        int idx = tid + k * 256;
        int c  = idx >> 6;           // / (SG/2)
        int t2 = (idx & 63) * 2;
        int gx = i0 + t2, gy = j0 + t2;
        float2 xv, yv;
        if (gx + 1 < TT) xv = *(const float2*)(X + c * TT + gx);
        else { xv.x = X[c * TT + min(gx, TT - 1)]; xv.y = X[c * TT + min(gx + 1, TT - 1)]; }
        if (gy + 1 < TT) yv = *(const float2*)(Y + c * TT + gy);
        else { yv.x = Y[c * TT + min(gy, TT - 1)]; yv.y = Y[c * TT + min(gy + 1, TT - 1)]; }
        px[k] = xv; py[k] = yv;
    }
}

// ------------------------------------------------------------------
// pass1 persistent (256 threads): dynamic tile tickets (order-free:
// disjoint dist writes, bit-pattern atomic min for colmin), per-tile
// body = validated r6/r8 engine with identical numerics; next tile's
// stage loads prefetched into registers during diag+epilogue (T14).
// ------------------------------------------------------------------
__global__ __launch_bounds__(256) void pass1_k(
        const float* __restrict__ X, const float* __restrict__ Y,
        const float* __restrict__ sx, const float* __restrict__ sy,
        unsigned* __restrict__ colmin,
        float* __restrict__ distbuf, int storeTiles,
        unsigned* __restrict__ ticket) {
    __shared__ __align__(16) char smem[SMEM_UNION + 1024];
    __shared__ int tile_s;
    unsigned* cmin_s = (unsigned*)(smem + SMEM_UNION);

    float (*Xs)[SG]   = (float (*)[SG])smem;
    float (*Ys)[SG]   = (float (*)[SG])(smem + STAGE_BYTES);
    float (*Sl)[SPAD] = (float (*)[SPAD])smem;   // alias over Xs/Ys

    const int tid = threadIdx.x;
    const int su = tid >> 4, sv = tid & 15;
    const int ri = su * 8, rj = sv * 8;

    if (tid == 0) tile_s = (int)atomicAdd(ticket, 1u);
    __syncthreads();
    int tile = tile_s;
    bool valid = (tile < NT2);

    float2 px[NPF], py[NPF];
    if (valid) {
        int by = tile / NTILE, bx = tile - by * NTILE;
        stage_prefetch(X, Y, by * TI, bx * TI, tid, px, py);
    }

    while (valid) {
        const int by = tile / NTILE, bx = tile - by * NTILE;
        const int i0 = by * TI, j0 = bx * TI;
        const bool store = (by < storeTiles);   // block-uniform

        // ---- A: prev tile's diag reads + colmin flush done ----
        __syncthreads();
        if (tid < 128) cmin_s[tid] = 0x7f800000u;

        // ---- stage writes from prefetched regs (values identical) ----
#pragma unroll
        for (int k = 0; k < NPF; ++k) {
            int idx = tid + k * 256;
            int c  = idx >> 6;
            int t2 = (idx & 63) * 2;
            *(float2*)&Xs[c][t2] = px[k];
            *(float2*)&Ys[c][t2] = py[k];
        }
        __syncthreads();   // B: stage visible

        // ---- S compute (validated order) ----
        float s[8][8];
#pragma unroll
        for (int a = 0; a < 8; ++a)
#pragma unroll
            for (int b = 0; b < 8; ++b) s[a][b] = 0.0f;

#pragma unroll 4
        for (int c = 0; c < CC; ++c) {
            float xv[8], yv[8];
            *(float4*)&xv[0] = *(const float4*)&Xs[c][su * 8];
            *(float4*)&xv[4] = *(const float4*)&Xs[c][su * 8 + 4];
            *(float4*)&yv[0] = *(const float4*)&Ys[c][sv * 4];
            *(float4*)&yv[4] = *(const float4*)&Ys[c][64 + sv * 4];
#pragma unroll
            for (int a = 0; a < 8; ++a)
#pragma unroll
                for (int b = 0; b < 8; ++b)
                    s[a][b] += xv[a] * yv[b];
        }
        __syncthreads();   // C: stage buffers dead

        if (tid == 0) tile_s = (int)atomicAdd(ticket, 1u);

        // ---- S store (swizzled, aliases stage) ----
#pragma unroll
        for (int a = 0; a < 8; ++a) {
            int row = su * 8 + a;
            int swz = ((row >> 3) & 3) << 2;
            *(float4*)&Sl[row][(sv * 4) ^ swz]      = make_float4(s[a][0], s[a][1], s[a][2], s[a][3]);
            *(float4*)&Sl[row][(64 + sv * 4) ^ swz] = make_float4(s[a][4], s[a][5], s[a][6], s[a][7]);
        }
        __syncthreads();   // D: S visible (and tile_s written)

        const int ntile = tile_s;
        const bool nvalid = (ntile < NT2);
        if (nvalid) {       // prefetch next tile; overlaps diag+epilogue
            int nby = ntile / NTILE, nbx = ntile - nby * NTILE;
            stage_prefetch(X, Y, nby * TI, nbx * TI, tid, px, py);
        }

        // ---- diagonal-band dot accumulation (ascending k: bit-identical) ----
        float dot[8][8];
#pragma unroll
        for (int a = 0; a < 8; ++a)
#pragma unroll
            for (int b = 0; b < 8; ++b) dot[a][b] = 0.0f;

#pragma unroll
        for (int r = 0; r < 14; ++r) {
            int row = ri + r;          // up to 133: stray reads stay inside smem, masked
            int swz = ((row >> 3) & 3) << 2;
            float f[14];
            *(float4*)&f[0]  = *(const float4*)&Sl[row][(rj)      ^ swz];
            *(float4*)&f[4]  = *(const float4*)&Sl[row][(rj + 4)  ^ swz];
            *(float4*)&f[8]  = *(const float4*)&Sl[row][(rj + 8)  ^ swz];
            *(float2*)&f[12] = *(const float2*)&Sl[row][(rj + 12) ^ swz];
#pragma unroll
            for (int a = 0; a < 8; ++a) {
                const int k = r - a;
                if (k >= 0 && k < PP) {
#pragma unroll
                    for (int b = 0; b < 8; ++b)
                        dot[a][b] += f[b + k];
                }
            }
        }

        // ---- epilogue: dist, column minima, optional store ----
        const int gj0 = j0 + rj;
        bool bv[8]; float syv[8];
#pragma unroll
        for (int b = 0; b < 8; ++b) {
            int lj = rj + b, gj = gj0 + b;
            bv[b] = (lj < TI && gj < NN);
            syv[b] = bv[b] ? sy[gj] : 0.0f;
        }
        const bool fullCols = (rj + 7 < TI) && (gj0 + 7 < NN);  // thread-uniform
        const bool al16 = ((gj0 & 3) == 0);                     // block-uniform

        float cm[8];
#pragma unroll
        for (int b = 0; b < 8; ++b) cm[b] = __uint_as_float(0x7f800000u);

#pragma unroll
        for (int a = 0; a < 8; ++a) {
            int li = ri + a, gi = i0 + li;
            if (li >= TI || gi >= NN) continue;
            float sxi = sx[gi];
            float d8[8];
#pragma unroll
            for (int b = 0; b < 8; ++b) {
                d8[b] = (sxi + syv[b] - 2.0f * dot[a][b]) * INV_D;
                if (bv[b]) cm[b] = fminf(cm[b], d8[b]);
            }
            if (store) {
                float* drow = distbuf + (size_t)gi * TT + gj0;
                if (fullCols) {
                    if (al16) {
                        *(float4*)&drow[0] = make_float4(d8[0], d8[1], d8[2], d8[3]);
                        *(float4*)&drow[4] = make_float4(d8[4], d8[5], d8[6], d8[7]);
                    } else {   // gj0 % 4 == 2: 8B / 16B / 8B, all naturally aligned
                        *(float2*)&drow[0] = make_float2(d8[0], d8[1]);
                        *(float4*)&drow[2] = make_float4(d8[2], d8[3], d8[4], d8[5]);
                        *(float2*)&drow[6] = make_float2(d8[6], d8[7]);
                    }
                } else {
#pragma unroll
                    for (int b = 0; b < 8; ++b)
                        if (bv[b]) drow[b] = d8[b];
                }
            }
        }
#pragma unroll
        for (int b = 0; b < 8; ++b)
            if (bv[b]) atomicMin(&cmin_s[rj + b], __float_as_uint(cm[b]));
        __syncthreads();   // E: cmin_s complete
        if (tid < TI) {
            int gj = j0 + tid;
            if (gj < NN) atomicMin(&colmin[gj], cmin_s[tid]);
        }

        tile = ntile; valid = nvalid;
    }
}

// ------------------------------------------------------------------
// pass2 stream: SROWS dist rows per block (colmin loads amortized,
// MLP via 10 outstanding b128/iter). Same nd = d/(alpha+cm) and
// (bits<<32)|j packing; u64-min partition-independent -> bit-identical.
// FULL: writes nnf[i] + fixed-point qsum; else packed[i].
// ------------------------------------------------------------------
template<bool FULL>
__global__ __launch_bounds__(256) void pass2_stream_k(
        const float* __restrict__ distbuf, const unsigned* __restrict__ colmin,
        unsigned long long* __restrict__ packed,
        int* __restrict__ nnf, unsigned long long* __restrict__ qsum, int nrows) {
    const int i0 = blockIdx.x * SROWS;
    const float* row0 = distbuf + (size_t)i0 * TT;
    const float* cmf = (const float*)colmin;   // bit pattern of nonneg floats

    unsigned long long best[SROWS];
#pragma unroll
    for (int r = 0; r < SROWS; ++r) best[r] = ~0ULL;

    for (int jb = threadIdx.x * 8; jb < NN; jb += 2048) {
        float4 c4a = *(const float4*)(cmf + jb);
        float4 c4b = *(const float4*)(cmf + jb + 4);
        float acm[8];
#pragma unroll
        for (int e = 0; e < 8; ++e)
            acm[e] = ALPHA_C + ((e < 4) ? (&c4a.x)[e] : (&c4b.x)[e - 4]);
#pragma unroll
        for (int r = 0; r < SROWS; ++r) {
            const float* row = row0 + (size_t)r * TT;
            float4 d4a = *(const float4*)(row + jb);
            float4 d4b = *(const float4*)(row + jb + 4);
#pragma unroll
            for (int e = 0; e < 8; ++e) {
                int j = jb + e;
                if (j < NN) {
                    float d  = (e < 4) ? (&d4a.x)[e] : (&d4b.x)[e - 4];
                    float nd = d / acm[e];    // exact division — matches validated path
                    unsigned long long pk =
                        ((unsigned long long)__float_as_uint(nd) << 32) | (unsigned)j;
                    best[r] = (pk < best[r]) ? pk : best[r];
                }
            }
        }
    }
#pragma unroll
    for (int r = 0; r < SROWS; ++r)
#pragma unroll
        for (int off = 32; off > 0; off >>= 1) {
            unsigned long long o = __shfl_down(best[r], off, 64);
            best[r] = (o < best[r]) ? o : best[r];
        }
    __shared__ unsigned long long wb[4][SROWS];
    int lane = threadIdx.x & 63, wid = threadIdx.x >> 6;
    if (lane == 0) {
#pragma unroll
        for (int r = 0; r < SROWS; ++r) wb[wid][r] = best[r];
    }
    __syncthreads();
    if (threadIdx.x < SROWS) {
        int r = threadIdx.x;
        int i = i0 + r;
        if (i < nrows) {
            unsigned long long b0 = wb[0][r];
            b0 = (wb[1][r] < b0) ? wb[1][r] : b0;
            b0 = (wb[2][r] < b0) ? wb[2][r] : b0;
            b0 = (wb[3][r] < b0) ? wb[3][r] : b0;
            if (FULL) {
                int j = (int)(b0 & 0xffffffffu);
                nnf[i] = j;
                float dval = distbuf[(size_t)i * TT + j];   // bit-exact stored dist
                atomicAdd(qsum, (unsigned long long)(long long)(dval * QSCALE));
            } else {
                packed[i] = b0;   // stream owns stored rows entirely
            }
        }
    }
}

// ------------------------------------------------------------------
// tile engine (256 threads) for the hybrid fallback pass2 — validated,
// unchanged.
// ------------------------------------------------------------------
__device__ __forceinline__ void tile_dots256(const float* __restrict__ X,
                                             const float* __restrict__ Y,
                                             int i0, int j0, char* smem,
                                             float dot[8][8]) {
    float (*Xs)[SG]   = (float (*)[SG])smem;
    float (*Ys)[SG]   = (float (*)[SG])(smem + STAGE_BYTES);
    float (*Sl)[SPAD] = (float (*)[SPAD])smem;
    const int tid = threadIdx.x;

    for (int idx = tid; idx < CC * SG / 2; idx += 256) {
        int c  = idx >> 6;
        int t2 = (idx & 63) * 2;
        int gx = i0 + t2, gy = j0 + t2;
        float2 xv, yv;
        if (gx + 1 < TT) xv = *(const float2*)(X + c * TT + gx);
        else { xv.x = X[c * TT + min(gx, TT - 1)]; xv.y = X[c * TT + min(gx + 1, TT - 1)]; }
        if (gy + 1 < TT) yv = *(const float2*)(Y + c * TT + gy);
        else { yv.x = Y[c * TT + min(gy, TT - 1)]; yv.y = Y[c * TT + min(gy + 1, TT - 1)]; }
        *(float2*)&Xs[c][t2] = xv;
        *(float2*)&Ys[c][t2] = yv;
    }
    __syncthreads();

    const int su = tid >> 4, sv = tid & 15;
    float s[8][8];
#pragma unroll
    for (int a = 0; a < 8; ++a)
#pragma unroll
        for (int b = 0; b < 8; ++b) s[a][b] = 0.0f;

#pragma unroll 4
    for (int c = 0; c < CC; ++c) {
        float xv[8], yv[8];
        *(float4*)&xv[0] = *(const float4*)&Xs[c][su * 8];
        *(float4*)&xv[4] = *(const float4*)&Xs[c][su * 8 + 4];
        *(float4*)&yv[0] = *(const float4*)&Ys[c][sv * 4];
        *(float4*)&yv[4] = *(const float4*)&Ys[c][64 + sv * 4];
#pragma unroll
        for (int a = 0; a < 8; ++a)
#pragma unroll
            for (int b = 0; b < 8; ++b)
                s[a][b] += xv[a] * yv[b];
    }
    __syncthreads();

#pragma unroll
    for (int a = 0; a < 8; ++a) {
        int row = su * 8 + a;
        int swz = ((row >> 3) & 3) << 2;
        *(float4*)&Sl[row][(sv * 4) ^ swz]      = make_float4(s[a][0], s[a][1], s[a][2], s[a][3]);
        *(float4*)&Sl[row][(64 + sv * 4) ^ swz] = make_float4(s[a][4], s[a][5], s[a][6], s[a][7]);
    }
    __syncthreads();

    const int ri = (tid >> 4) * 8, rj = (tid & 15) * 8;
#pragma unroll
    for (int a = 0; a < 8; ++a)
#pragma unroll
        for (int b = 0; b < 8; ++b) dot[a][b] = 0.0f;

#pragma unroll
    for (int r = 0; r < 14; ++r) {
        int row = ri + r;
        int swz = ((row >> 3) & 3) << 2;
        float f[14];
        *(float4*)&f[0]  = *(const float4*)&Sl[row][(rj)      ^ swz];
        *(float4*)&f[4]  = *(const float4*)&Sl[row][(rj + 4)  ^ swz];
        *(float4*)&f[8]  = *(const float4*)&Sl[row][(rj + 8)  ^ swz];
        *(float2*)&f[12] = *(const float2*)&Sl[row][(rj + 12) ^ swz];
#pragma unroll
        for (int a = 0; a < 8; ++a) {
            const int k = r - a;
            if (k >= 0 && k < PP) {
#pragma unroll
                for (int b = 0; b < 8; ++b)
                    dot[a][b] += f[b + k];
            }
        }
    }
}

// ------------------------------------------------------------------
// pass2b (hybrid fallback): recompute variant for unstored i-tiles.
// ------------------------------------------------------------------
__global__ __launch_bounds__(256) void pass2_k(
        const float* __restrict__ X, const float* __restrict__ Y,
        const float* __restrict__ sx, const float* __restrict__ sy,
        const unsigned* __restrict__ colmin,
        unsigned long long* __restrict__ packed, int itile_ofs) {
    __shared__ __align__(16) char smem[SMEM_UNION + 1024];
    unsigned long long* pmin_s = (unsigned long long*)(smem + SMEM_UNION);

    const int i0 = (itile_ofs + blockIdx.y) * TI;
    const int j0 = blockIdx.x * TI;
    const int tid = threadIdx.x;
    if (tid < TI) pmin_s[tid] = ~0ULL;

    float dot[8][8];
    tile_dots256(X, Y, i0, j0, smem, dot);

    const int ri = (tid >> 4) * 8, rj = (tid & 15) * 8;
    const int gj0 = j0 + rj;

    bool bv[8]; float syv[8], acm[8];
#pragma unroll
    for (int b = 0; b < 8; ++b) {
        int lj = rj + b, gj = gj0 + b;
        bv[b] = (lj < TI && gj < NN);
        syv[b] = bv[b] ? sy[gj] : 0.0f;
        acm[b] = bv[b] ? (ALPHA_C + __uint_as_float(colmin[gj])) : 1.0f;
    }

#pragma unroll
    for (int a = 0; a < 8; ++a) {
        int li = ri + a, gi = i0 + li;
        if (li >= TI || gi >= NN) continue;
        float sxi = sx[gi];
        unsigned long long best = ~0ULL;
#pragma unroll
        for (int b = 0; b < 8; ++b) {
            if (bv[b]) {
                float d  = (sxi + syv[b] - 2.0f * dot[a][b]) * INV_D;
                float nd = d / acm[b];   // exact division — do NOT replace with reciprocal
                unsigned long long pk =
                    ((unsigned long long)__float_as_uint(nd) << 32) | (unsigned)(gj0 + b);
                best = (pk < best) ? pk : best;
            }
        }
        atomicMin(&pmin_s[li], best);
    }
    __syncthreads();
    if (tid < TI) {
        int gi = i0 + tid;
        if (gi < NN) atomicMin(&packed[gi], pmin_s[tid]);
    }
}

// ------------------------------------------------------------------
// finalize (hybrid path only): nnf[i], dists[i] recompute, fixed-point sum
// ------------------------------------------------------------------
__global__ void finalize_kernel(const float* __restrict__ X, const float* __restrict__ Y,
                                const float* __restrict__ sx, const float* __restrict__ sy,
                                const unsigned long long* __restrict__ packed,
                                int* __restrict__ nnf, unsigned long long* __restrict__ qsum) {
    int i = blockIdx.x * 256 + threadIdx.x;
    long long q = 0;
    if (i < NN) {
        int j = (int)(packed[i] & 0xffffffffu);
        nnf[i] = j;
        float dot = 0.0f;
        for (int c = 0; c < CC; ++c) {
            const float* xr = X + c * TT + i;
            const float* yr = Y + c * TT + j;
#pragma unroll
            for (int k = 0; k < PP; ++k) dot += xr[k] * yr[k];
        }
        float dval = (sx[i] + sy[j] - 2.0f * dot) * INV_D;
        q = (long long)(dval * QSCALE);
    }
    __shared__ long long red[256];
    red[threadIdx.x] = q;
    __syncthreads();
    for (int s = 128; s > 0; s >>= 1) {
        if (threadIdx.x < s) red[threadIdx.x] += red[threadIdx.x + s];
        __syncthreads();
    }
    if (threadIdx.x == 0) atomicAdd(qsum, (unsigned long long)red[0]);
}

// ------------------------------------------------------------------
// fold: gather-form overlap-add + counts + mean write
// ------------------------------------------------------------------
__global__ void fold_kernel(const float* __restrict__ Y, const int* __restrict__ nnf,
                            const unsigned long long* __restrict__ qsum,
                            float* __restrict__ out) {
    int idx = blockIdx.x * 256 + threadIdx.x;
    if (idx < CC * TT) {
        int c = idx >> 13;          // /8192
        int t = idx & (TT - 1);
        float acc = 0.0f;
        int cnt = 0;
#pragma unroll
        for (int k = 0; k < PP; ++k) {
            int i = t - k;
            if (i >= 0 && i < NN) {
                acc += Y[c * TT + nnf[i] + k];
                cnt++;
            }
        }
        out[idx] = acc / (float)cnt;
    }
    if (idx == 0) {
        double m = (double)*qsum * (1.0 / (double)QSCALE) / (double)NN;
        out[CC * TT] = (float)m;
    }
}

// ------------------------------------------------------------------
extern "C" void kernel_launch(void* const* d_in, const int* in_sizes, int n_in,
                              void* d_out, int out_size, void* d_ws, size_t ws_size,
                              hipStream_t stream) {
    const float* X = (const float*)d_in[0];
    const float* Y = (const float*)d_in[1];
    float* out = (float*)d_out;

    // ---- ws partition: dist rows at front, 192 KiB scratch at tail ----
    char* w = (char*)d_ws;
    size_t base = 0;
    if (ws_size > TAIL_BYTES) base = ((ws_size - TAIL_BYTES) / 32768) * 32768;
    unsigned long long* packed = (unsigned long long*)(w + base);            // 65536
    unsigned*           colmin = (unsigned*)(w + base + 65536);              // 32768
    float*              sx     = (float*)(w + base + 98304);                 // 32744
    float*              sy     = (float*)(w + base + 131072);                // 32744
    int*                nnf    = (int*)(w + base + 163840);                  // 32744
    unsigned*           ticket = (unsigned*)(w + base + 196592);             // 4
    unsigned long long* qsum   = (unsigned long long*)(w + base + 196600);   // 8
    float*              distbuf = (float*)w;                                 // up to base bytes

    // how many whole i-tiles of dist rows fit in [0, base)?
    const long storeRows = (long)(base / ((size_t)TT * 4));
    int storeTiles = 0;
    for (int nT = 1; nT <= NTILE; ++nT) {
        long need = (long)nT * TI; if (need > NN) need = NN;
        if (need <= storeRows) storeTiles = nT; else break;
    }
    const int SR = (storeTiles * TI < NN) ? storeTiles * TI : NN;  // stored row count
    const bool full = (storeTiles >= NTILE);

    prep_kernel<<<dim3((TT + 255) / 256, 2), 256, 0, stream>>>(
        X, Y, sx, sy, colmin, packed, qsum, ticket);

    pass1_k<<<512, 256, 0, stream>>>(X, Y, sx, sy, colmin, distbuf, storeTiles, ticket);

    if (full) {
        pass2_stream_k<true><<<(NN + SROWS - 1) / SROWS, 256, 0, stream>>>(
            distbuf, colmin, packed, nnf, qsum, NN);
    } else {
        if (SR > 0)
            pass2_stream_k<false><<<(SR + SROWS - 1) / SROWS, 256, 0, stream>>>(
                distbuf, colmin, packed, nnf, qsum, SR);
        if (storeTiles < NTILE) {
            dim3 grid2(NTILE, NTILE - storeTiles);
            pass2_k<<<grid2, 256, 0, stream>>>(X, Y, sx, sy, colmin, packed, storeTiles);
        }
        finalize_kernel<<<(NN + 255) / 256, 256, 0, stream>>>(X, Y, sx, sy, packed, nnf, qsum);
    }
    fold_kernel<<<(CC * TT + 255) / 256, 256, 0, stream>>>(Y, nnf, qsum, out);
}

// Round 10
// 290.740 us; speedup vs baseline: 1.3358x; 1.3358x over previous
//
#include <hip/hip_runtime.h>
#include <stdint.h>

// Problem constants (from reference)
#define TT 8192          // time length
#define CC 72            // channels
#define PP 7             // patch size
#define NN (TT - PP + 1) // 8186 patches
#define DD (CC * PP)     // 504 patch dim

#define TI 122           // output tile (both dims)
#define SG 128           // S grid = TI + PP - 1 = 128 exactly
#define SPAD 132         // padded S row stride (floats), 16B-aligned rows
#define NTILE ((NN + TI - 1) / TI)   // 68
#define NT2   (NTILE * NTILE)        // 4624
#define GRID1 4608                   // 9 exact rounds of 512 resident blocks

#define STAGE_BYTES (CC * SG * 4)            // 36864 per buffer
#define SMEM_UNION  (2 * STAGE_BYTES)        // 73728 (Xs+Ys, aliased by S)

// tail scratch block: 192 KiB total, placed at end of ws so dist can use the front
#define TAIL_BYTES 196608

#define SROWS 4          // dist rows per stream block (colmin reuse + MLP)

constexpr float INV_D = 1.0f / (float)DD;
constexpr float ALPHA_C = 0.01f;
constexpr float QSCALE = 67108864.0f;        // 2^26 fixed-point for deterministic mean

// ------------------------------------------------------------------
// prep: patch norms sx/sy (split across gridDim.y; per-i accumulation
// order unchanged -> bit-identical); init colmin, packed, qsum.
// ------------------------------------------------------------------
__global__ void prep_kernel(const float* __restrict__ X, const float* __restrict__ Y,
                            float* __restrict__ sx, float* __restrict__ sy,
                            unsigned* __restrict__ colmin,
                            unsigned long long* __restrict__ packed,
                            unsigned long long* __restrict__ qsum) {
    int i = blockIdx.x * 256 + threadIdx.x;
    if (blockIdx.y == 0) {
        if (i == 0) *qsum = 0ULL;
        if (i < TT) { colmin[i] = 0x7f800000u; packed[i] = ~0ULL; }
        if (i < NN) {
            float ax = 0.0f;
            for (int c = 0; c < CC; ++c) {
                const float* xr = X + c * TT + i;
#pragma unroll
                for (int k = 0; k < PP; ++k) { float v = xr[k]; ax += v * v; }
            }
            sx[i] = ax;
        }
    } else {
        if (i < NN) {
            float ay = 0.0f;
            for (int c = 0; c < CC; ++c) {
                const float* yr = Y + c * TT + i;
#pragma unroll
                for (int k = 0; k < PP; ++k) { float w = yr[k]; ay += w * w; }
            }
            sy[i] = ay;
        }
    }
}

// ------------------------------------------------------------------
// tile engine, 256 threads — the VALIDATED r6/r8 engine, unchanged.
// 8x8 per-thread S blocking (16 FMA per ds_read_b128 — keep this ratio;
// 512-thread 4x8 regressed r7; reg-prefetch persistent regressed r9
// via VGPR 220 -> 1 block/CU). Bit-identical numerics.
// ------------------------------------------------------------------
__device__ __forceinline__ void tile_dots256(const float* __restrict__ X,
                                             const float* __restrict__ Y,
                                             int i0, int j0, char* smem,
                                             float dot[8][8]) {
    float (*Xs)[SG]   = (float (*)[SG])smem;
    float (*Ys)[SG]   = (float (*)[SG])(smem + STAGE_BYTES);
    float (*Sl)[SPAD] = (float (*)[SPAD])smem;   // alias over Xs/Ys
    const int tid = threadIdx.x;

    // ---- stage (float2: i0/j0 always even since TI=122 is even) ----
    for (int idx = tid; idx < CC * SG / 2; idx += 256) {
        int c  = idx >> 6;           // / (SG/2)
        int t2 = (idx & 63) * 2;
        int gx = i0 + t2, gy = j0 + t2;
        float2 xv, yv;
        if (gx + 1 < TT) xv = *(const float2*)(X + c * TT + gx);
        else { xv.x = X[c * TT + min(gx, TT - 1)]; xv.y = X[c * TT + min(gx + 1, TT - 1)]; }
        if (gy + 1 < TT) yv = *(const float2*)(Y + c * TT + gy);
        else { yv.x = Y[c * TT + min(gy, TT - 1)]; yv.y = Y[c * TT + min(gy + 1, TT - 1)]; }
        *(float2*)&Xs[c][t2] = xv;
        *(float2*)&Ys[c][t2] = yv;
    }
    __syncthreads();

    // ---- S compute: thread (su,sv) -> rows su*8..+7, cols {4sv..+3, 64+4sv..+3}
    const int su = tid >> 4, sv = tid & 15;
    float s[8][8];
#pragma unroll
    for (int a = 0; a < 8; ++a)
#pragma unroll
        for (int b = 0; b < 8; ++b) s[a][b] = 0.0f;

#pragma unroll 4
    for (int c = 0; c < CC; ++c) {
        float xv[8], yv[8];
        *(float4*)&xv[0] = *(const float4*)&Xs[c][su * 8];
        *(float4*)&xv[4] = *(const float4*)&Xs[c][su * 8 + 4];
        *(float4*)&yv[0] = *(const float4*)&Ys[c][sv * 4];
        *(float4*)&yv[4] = *(const float4*)&Ys[c][64 + sv * 4];
#pragma unroll
        for (int a = 0; a < 8; ++a)
#pragma unroll
            for (int b = 0; b < 8; ++b)
                s[a][b] += xv[a] * yv[b];
    }
    __syncthreads();   // stage buffers dead; safe to overwrite with S

#pragma unroll
    for (int a = 0; a < 8; ++a) {
        int row = su * 8 + a;
        int swz = ((row >> 3) & 3) << 2;
        *(float4*)&Sl[row][(sv * 4) ^ swz]      = make_float4(s[a][0], s[a][1], s[a][2], s[a][3]);
        *(float4*)&Sl[row][(64 + sv * 4) ^ swz] = make_float4(s[a][4], s[a][5], s[a][6], s[a][7]);
    }
    __syncthreads();

    // ---- diagonal-band dot accumulation (contiguous 8x8 per thread) ----
    const int ri = (tid >> 4) * 8, rj = (tid & 15) * 8;
#pragma unroll
    for (int a = 0; a < 8; ++a)
#pragma unroll
        for (int b = 0; b < 8; ++b) dot[a][b] = 0.0f;

#pragma unroll
    for (int r = 0; r < 14; ++r) {
        int row = ri + r;          // up to 133: stray reads stay inside smem, masked
        int swz = ((row >> 3) & 3) << 2;
        float f[14];
        *(float4*)&f[0]  = *(const float4*)&Sl[row][(rj)      ^ swz];
        *(float4*)&f[4]  = *(const float4*)&Sl[row][(rj + 4)  ^ swz];
        *(float4*)&f[8]  = *(const float4*)&Sl[row][(rj + 8)  ^ swz];
        *(float2*)&f[12] = *(const float2*)&Sl[row][(rj + 12) ^ swz];
#pragma unroll
        for (int a = 0; a < 8; ++a) {
            const int k = r - a;
            if (k >= 0 && k < PP) {
#pragma unroll
                for (int b = 0; b < 8; ++b)
                    dot[a][b] += f[b + k];   // ascending k: bit-identical
            }
        }
    }
}

// ------------------------------------------------------------------
// pass1 (256 threads, validated r8 body) with static 2-tile chaining:
// grid = 4608 (= 9 exact rounds of 512 resident blocks); the 16
// leftover tiles chain onto blocks 0..15. No atomics, no extra VGPR;
// tile->values is a pure function so results are bit-identical.
// ------------------------------------------------------------------
__global__ __launch_bounds__(256) void pass1_k(
        const float* __restrict__ X, const float* __restrict__ Y,
        const float* __restrict__ sx, const float* __restrict__ sy,
        unsigned* __restrict__ colmin,
        float* __restrict__ distbuf, int storeTiles) {
    __shared__ __align__(16) char smem[SMEM_UNION + 1024];
    unsigned* cmin_s = (unsigned*)(smem + SMEM_UNION);
    const int tid = threadIdx.x;

    for (int tile = blockIdx.x; tile < NT2; tile += GRID1) {
        const int by = tile / NTILE, bx = tile - by * NTILE;
        const int i0 = by * TI;
        const int j0 = bx * TI;
        const bool store = (by < storeTiles);   // block-uniform

        if (tid < 128) cmin_s[tid] = 0x7f800000u;

        float dot[8][8];
        tile_dots256(X, Y, i0, j0, smem, dot);

        const int ri = (tid >> 4) * 8, rj = (tid & 15) * 8;
        const int gj0 = j0 + rj;

        bool bv[8]; float syv[8];
#pragma unroll
        for (int b = 0; b < 8; ++b) {
            int lj = rj + b, gj = gj0 + b;
            bv[b] = (lj < TI && gj < NN);
            syv[b] = bv[b] ? sy[gj] : 0.0f;
        }
        const bool fullCols = (rj + 7 < TI) && (gj0 + 7 < NN);  // thread-uniform
        const bool al16 = ((gj0 & 3) == 0);                     // block-uniform

        float cm[8];
#pragma unroll
        for (int b = 0; b < 8; ++b) cm[b] = __uint_as_float(0x7f800000u);

#pragma unroll
        for (int a = 0; a < 8; ++a) {
            int li = ri + a, gi = i0 + li;
            if (li >= TI || gi >= NN) continue;
            float sxi = sx[gi];
            float d8[8];
#pragma unroll
            for (int b = 0; b < 8; ++b) {
                d8[b] = (sxi + syv[b] - 2.0f * dot[a][b]) * INV_D;
                if (bv[b]) cm[b] = fminf(cm[b], d8[b]);
            }
            if (store) {
                float* drow = distbuf + (size_t)gi * TT + gj0;
                if (fullCols) {
                    if (al16) {
                        *(float4*)&drow[0] = make_float4(d8[0], d8[1], d8[2], d8[3]);
                        *(float4*)&drow[4] = make_float4(d8[4], d8[5], d8[6], d8[7]);
                    } else {   // gj0 % 4 == 2: 8B / 16B / 8B, all naturally aligned
                        *(float2*)&drow[0] = make_float2(d8[0], d8[1]);
                        *(float4*)&drow[2] = make_float4(d8[2], d8[3], d8[4], d8[5]);
                        *(float2*)&drow[6] = make_float2(d8[6], d8[7]);
                    }
                } else {
#pragma unroll
                    for (int b = 0; b < 8; ++b)
                        if (bv[b]) drow[b] = d8[b];
                }
            }
        }
#pragma unroll
        for (int b = 0; b < 8; ++b)
            if (bv[b]) atomicMin(&cmin_s[rj + b], __float_as_uint(cm[b]));
        __syncthreads();   // cmin_s complete
        if (tid < TI) {
            int gj = j0 + tid;
            if (gj < NN) atomicMin(&colmin[gj], cmin_s[tid]);
        }
        __syncthreads();   // protect cmin_s / LDS reuse before next iteration
    }
}

// ------------------------------------------------------------------
// pass2 stream: SROWS dist rows per block (colmin loads amortized,
// MLP via 10 outstanding b128/iter). Same nd = d/(alpha+cm) and
// (bits<<32)|j packing; u64-min partition-independent -> bit-identical.
// FULL: writes nnf[i] + fixed-point qsum; else packed[i].
// ------------------------------------------------------------------
template<bool FULL>
__global__ __launch_bounds__(256) void pass2_stream_k(
        const float* __restrict__ distbuf, const unsigned* __restrict__ colmin,
        unsigned long long* __restrict__ packed,
        int* __restrict__ nnf, unsigned long long* __restrict__ qsum, int nrows) {
    const int i0 = blockIdx.x * SROWS;
    const float* row0 = distbuf + (size_t)i0 * TT;
    const float* cmf = (const float*)colmin;   // bit pattern of nonneg floats

    unsigned long long best[SROWS];
#pragma unroll
    for (int r = 0; r < SROWS; ++r) best[r] = ~0ULL;

    for (int jb = threadIdx.x * 8; jb < NN; jb += 2048) {
        float4 c4a = *(const float4*)(cmf + jb);
        float4 c4b = *(const float4*)(cmf + jb + 4);
        float acm[8];
#pragma unroll
        for (int e = 0; e < 8; ++e)
            acm[e] = ALPHA_C + ((e < 4) ? (&c4a.x)[e] : (&c4b.x)[e - 4]);
#pragma unroll
        for (int r = 0; r < SROWS; ++r) {
            const float* row = row0 + (size_t)r * TT;
            float4 d4a = *(const float4*)(row + jb);
            float4 d4b = *(const float4*)(row + jb + 4);
#pragma unroll
            for (int e = 0; e < 8; ++e) {
                int j = jb + e;
                if (j < NN) {
                    float d  = (e < 4) ? (&d4a.x)[e] : (&d4b.x)[e - 4];
                    float nd = d / acm[e];    // exact division — matches validated path
                    unsigned long long pk =
                        ((unsigned long long)__float_as_uint(nd) << 32) | (unsigned)j;
                    best[r] = (pk < best[r]) ? pk : best[r];
                }
            }
        }
    }
#pragma unroll
    for (int r = 0; r < SROWS; ++r)
#pragma unroll
        for (int off = 32; off > 0; off >>= 1) {
            unsigned long long o = __shfl_down(best[r], off, 64);
            best[r] = (o < best[r]) ? o : best[r];
        }
    __shared__ unsigned long long wb[4][SROWS];
    int lane = threadIdx.x & 63, wid = threadIdx.x >> 6;
    if (lane == 0) {
#pragma unroll
        for (int r = 0; r < SROWS; ++r) wb[wid][r] = best[r];
    }
    __syncthreads();
    if (threadIdx.x < SROWS) {
        int r = threadIdx.x;
        int i = i0 + r;
        if (i < nrows) {
            unsigned long long b0 = wb[0][r];
            b0 = (wb[1][r] < b0) ? wb[1][r] : b0;
            b0 = (wb[2][r] < b0) ? wb[2][r] : b0;
            b0 = (wb[3][r] < b0) ? wb[3][r] : b0;
            if (FULL) {
                int j = (int)(b0 & 0xffffffffu);
                nnf[i] = j;
                float dval = distbuf[(size_t)i * TT + j];   // bit-exact stored dist
                atomicAdd(qsum, (unsigned long long)(long long)(dval * QSCALE));
            } else {
                packed[i] = b0;   // stream owns stored rows entirely
            }
        }
    }
}

// ------------------------------------------------------------------
// pass2b (hybrid fallback): recompute variant for unstored i-tiles.
// ------------------------------------------------------------------
__global__ __launch_bounds__(256) void pass2_k(
        const float* __restrict__ X, const float* __restrict__ Y,
        const float* __restrict__ sx, const float* __restrict__ sy,
        const unsigned* __restrict__ colmin,
        unsigned long long* __restrict__ packed, int itile_ofs) {
    __shared__ __align__(16) char smem[SMEM_UNION + 1024];
    unsigned long long* pmin_s = (unsigned long long*)(smem + SMEM_UNION);

    const int i0 = (itile_ofs + blockIdx.y) * TI;
    const int j0 = blockIdx.x * TI;
    const int tid = threadIdx.x;
    if (tid < TI) pmin_s[tid] = ~0ULL;

    float dot[8][8];
    tile_dots256(X, Y, i0, j0, smem, dot);

    const int ri = (tid >> 4) * 8, rj = (tid & 15) * 8;
    const int gj0 = j0 + rj;

    bool bv[8]; float syv[8], acm[8];
#pragma unroll
    for (int b = 0; b < 8; ++b) {
        int lj = rj + b, gj = gj0 + b;
        bv[b] = (lj < TI && gj < NN);
        syv[b] = bv[b] ? sy[gj] : 0.0f;
        acm[b] = bv[b] ? (ALPHA_C + __uint_as_float(colmin[gj])) : 1.0f;
    }

#pragma unroll
    for (int a = 0; a < 8; ++a) {
        int li = ri + a, gi = i0 + li;
        if (li >= TI || gi >= NN) continue;
        float sxi = sx[gi];
        unsigned long long best = ~0ULL;
#pragma unroll
        for (int b = 0; b < 8; ++b) {
            if (bv[b]) {
                float d  = (sxi + syv[b] - 2.0f * dot[a][b]) * INV_D;
                float nd = d / acm[b];   // exact division — do NOT replace with reciprocal
                unsigned long long pk =
                    ((unsigned long long)__float_as_uint(nd) << 32) | (unsigned)(gj0 + b);
                best = (pk < best) ? pk : best;
            }
        }
        atomicMin(&pmin_s[li], best);
    }
    __syncthreads();
    if (tid < TI) {
        int gi = i0 + tid;
        if (gi < NN) atomicMin(&packed[gi], pmin_s[tid]);
    }
}

// ------------------------------------------------------------------
// finalize (hybrid path only): nnf[i], dists[i] recompute, fixed-point sum
// ------------------------------------------------------------------
__global__ void finalize_kernel(const float* __restrict__ X, const float* __restrict__ Y,
                                const float* __restrict__ sx, const float* __restrict__ sy,
                                const unsigned long long* __restrict__ packed,
                                int* __restrict__ nnf, unsigned long long* __restrict__ qsum) {
    int i = blockIdx.x * 256 + threadIdx.x;
    long long q = 0;
    if (i < NN) {
        int j = (int)(packed[i] & 0xffffffffu);
        nnf[i] = j;
        float dot = 0.0f;
        for (int c = 0; c < CC; ++c) {
            const float* xr = X + c * TT + i;
            const float* yr = Y + c * TT + j;
#pragma unroll
            for (int k = 0; k < PP; ++k) dot += xr[k] * yr[k];
        }
        float dval = (sx[i] + sy[j] - 2.0f * dot) * INV_D;
        q = (long long)(dval * QSCALE);
    }
    __shared__ long long red[256];
    red[threadIdx.x] = q;
    __syncthreads();
    for (int s = 128; s > 0; s >>= 1) {
        if (threadIdx.x < s) red[threadIdx.x] += red[threadIdx.x + s];
        __syncthreads();
    }
    if (threadIdx.x == 0) atomicAdd(qsum, (unsigned long long)red[0]);
}

// ------------------------------------------------------------------
// fold: gather-form overlap-add + counts + mean write
// ------------------------------------------------------------------
__global__ void fold_kernel(const float* __restrict__ Y, const int* __restrict__ nnf,
                            const unsigned long long* __restrict__ qsum,
                            float* __restrict__ out) {
    int idx = blockIdx.x * 256 + threadIdx.x;
    if (idx < CC * TT) {
        int c = idx >> 13;          // /8192
        int t = idx & (TT - 1);
        float acc = 0.0f;
        int cnt = 0;
#pragma unroll
        for (int k = 0; k < PP; ++k) {
            int i = t - k;
            if (i >= 0 && i < NN) {
                acc += Y[c * TT + nnf[i] + k];
                cnt++;
            }
        }
        out[idx] = acc / (float)cnt;
    }
    if (idx == 0) {
        double m = (double)*qsum * (1.0 / (double)QSCALE) / (double)NN;
        out[CC * TT] = (float)m;
    }
}

// ------------------------------------------------------------------
extern "C" void kernel_launch(void* const* d_in, const int* in_sizes, int n_in,
                              void* d_out, int out_size, void* d_ws, size_t ws_size,
                              hipStream_t stream) {
    const float* X = (const float*)d_in[0];
    const float* Y = (const float*)d_in[1];
    float* out = (float*)d_out;

    // ---- ws partition: dist rows at front, 192 KiB scratch at tail ----
    char* w = (char*)d_ws;
    size_t base = 0;
    if (ws_size > TAIL_BYTES) base = ((ws_size - TAIL_BYTES) / 32768) * 32768;
    unsigned long long* packed = (unsigned long long*)(w + base);            // 65536
    unsigned*           colmin = (unsigned*)(w + base + 65536);              // 32768
    float*              sx     = (float*)(w + base + 98304);                 // 32744
    float*              sy     = (float*)(w + base + 131072);                // 32744
    int*                nnf    = (int*)(w + base + 163840);                  // 32744
    unsigned long long* qsum   = (unsigned long long*)(w + base + 196600);   // 8
    float*              distbuf = (float*)w;                                 // up to base bytes

    // how many whole i-tiles of dist rows fit in [0, base)?
    const long storeRows = (long)(base / ((size_t)TT * 4));
    int storeTiles = 0;
    for (int nT = 1; nT <= NTILE; ++nT) {
        long need = (long)nT * TI; if (need > NN) need = NN;
        if (need <= storeRows) storeTiles = nT; else break;
    }
    const int SR = (storeTiles * TI < NN) ? storeTiles * TI : NN;  // stored row count
    const bool full = (storeTiles >= NTILE);

    prep_kernel<<<dim3((TT + 255) / 256, 2), 256, 0, stream>>>(
        X, Y, sx, sy, colmin, packed, qsum);

    pass1_k<<<GRID1, 256, 0, stream>>>(X, Y, sx, sy, colmin, distbuf, storeTiles);

    if (full) {
        pass2_stream_k<true><<<(NN + SROWS - 1) / SROWS, 256, 0, stream>>>(
            distbuf, colmin, packed, nnf, qsum, NN);
    } else {
        if (SR > 0)
            pass2_stream_k<false><<<(SR + SROWS - 1) / SROWS, 256, 0, stream>>>(
                distbuf, colmin, packed, nnf, qsum, SR);
        if (storeTiles < NTILE) {
            dim3 grid2(NTILE, NTILE - storeTiles);
            pass2_k<<<grid2, 256, 0, stream>>>(X, Y, sx, sy, colmin, packed, storeTiles);
        }
        finalize_kernel<<<(NN + 255) / 256, 256, 0, stream>>>(X, Y, sx, sy, packed, nnf, qsum);
    }
    fold_kernel<<<(CC * TT + 255) / 256, 256, 0, stream>>>(Y, nnf, qsum, out);
}